// Round 1
// baseline (734.069 us; speedup 1.0000x reference)
//
#include <hip/hip_runtime.h>
#include <stdint.h>

#define EPS_F 1e-7f

typedef float f32x4 __attribute__((ext_vector_type(4)));
typedef short short8 __attribute__((ext_vector_type(8)));

__device__ __forceinline__ short f2bf(float f) {
  unsigned u = __float_as_uint(f);
  unsigned r = u + 0x7FFFu + ((u >> 16) & 1u);
  return (short)(r >> 16);
}

// ---------------------------------------------------------------------------
// Build piecewise-linear table for  f(x) = relu(x*w1 + b1) @ W2 + b2
// (scalar x -> R^256).  129 segments, knots at -b1_j/w1_j.
// One block, 256 threads.
// ---------------------------------------------------------------------------
__global__ void build_table_kernel(const float* __restrict__ w1, const float* __restrict__ b1,
                                   const float* __restrict__ w2, const float* __restrict__ b2,
                                   float* __restrict__ knots, float* __restrict__ segA,
                                   float* __restrict__ segB) {
  __shared__ float s_w1[128], s_b1[128], s_kx[128];
  __shared__ int s_sidx[128];
  __shared__ unsigned char s_act0[128];
  int t = threadIdx.x;
  if (t < 128) {
    float w = w1[t], b = b1[t];
    s_w1[t] = w; s_b1[t] = b;
    float kx = (w != 0.0f) ? (-b / w) : 3.4e38f;
    s_kx[t] = kx;
    s_act0[t] = (w < 0.0f) || (w == 0.0f && b > 0.0f);  // active at x = -inf
  }
  __syncthreads();
  if (t < 128) {
    float kx = s_kx[t];
    int r = 0;
    for (int i = 0; i < 128; ++i) {
      float o = s_kx[i];
      if (o < kx || (o == kx && i < t)) ++r;
    }
    s_sidx[r] = t;
  }
  __syncthreads();
  if (t < 128) knots[t] = s_kx[s_sidx[t]];
  // per-dim prefix walk over sorted knots (t = output dim 0..255)
  float A = 0.0f, B = b2[t];
  for (int j = 0; j < 128; ++j) {
    if (s_act0[j]) {
      float w2v = w2[j * 256 + t];
      A += s_w1[j] * w2v;
      B += s_b1[j] * w2v;
    }
  }
  segA[t] = A; segB[t] = B;
  for (int sN = 0; sN < 128; ++sN) {
    int j = s_sidx[sN];
    float sign = s_act0[j] ? -1.0f : 1.0f;
    float w2v = w2[j * 256 + t];
    A += sign * s_w1[j] * w2v;
    B += sign * s_b1[j] * w2v;
    segA[(sN + 1) * 256 + t] = A;
    segB[(sN + 1) * 256 + t] = B;
  }
}

// ---------------------------------------------------------------------------
// Apply encoder table to scalar rows -> f32 [n,256]
// ---------------------------------------------------------------------------
__global__ void apply_enc_kernel(const float* __restrict__ in, int nrows,
                                 const float* __restrict__ knots, const float* __restrict__ segA,
                                 const float* __restrict__ segB, float* __restrict__ out) {
  __shared__ float s_kx[128];
  int t = threadIdx.x;
  if (t < 128) s_kx[t] = knots[t];
  __syncthreads();
  int r0 = blockIdx.x * 16;
  int rEnd = r0 + 16;
  if (rEnd > nrows) rEnd = nrows;
  for (int r = r0; r < rEnd; ++r) {
    float x = in[r];
    int lo = 0, hi = 128;
    while (lo < hi) { int mid = (lo + hi) >> 1; if (s_kx[mid] < x) lo = mid + 1; else hi = mid; }
    out[(size_t)r * 256 + t] = fmaf(segA[lo * 256 + t], x, segB[lo * 256 + t]);
  }
}

__global__ void zero_kernel(int* __restrict__ p, int n) {
  int i = blockIdx.x * blockDim.x + threadIdx.x;
  if (i < n) p[i] = 0;
}

__global__ void hist_kernel(const int* __restrict__ dst, int E, int* __restrict__ counts) {
  int i = blockIdx.x * blockDim.x + threadIdx.x;
  if (i < E) atomicAdd(&counts[dst[i]], 1);
}

// single block, 256 threads: exclusive scan of counts[0..n) -> row_start[0..n]
__global__ void scan_kernel(const int* __restrict__ counts, int* __restrict__ row_start, int n) {
  __shared__ int tmp[256];
  __shared__ int carry;
  int t = threadIdx.x;
  if (t == 0) carry = 0;
  __syncthreads();
  for (int base = 0; base < n; base += 256) {
    int i = base + t;
    int v = (i < n) ? counts[i] : 0;
    tmp[t] = v;
    __syncthreads();
    for (int off = 1; off < 256; off <<= 1) {
      int add = (t >= off) ? tmp[t - off] : 0;
      __syncthreads();
      tmp[t] += add;
      __syncthreads();
    }
    int incl = tmp[t];
    int total = tmp[255];
    if (i < n) row_start[i] = carry + incl - v;
    __syncthreads();
    if (t == 0) carry += total;
    __syncthreads();
  }
  if (t == 0) row_start[n] = carry;
}

// fill CSR: per edge, slot under its dst; entry packs {src | seg<<17, bits(x)}
__global__ void fill_kernel(const int* __restrict__ srcA, const int* __restrict__ dstA,
                            const float* __restrict__ eattr, int E,
                            const int* __restrict__ row_start, int* __restrict__ cursor,
                            const float* __restrict__ knotsE, int2* __restrict__ csr) {
  __shared__ float s_kx[128];
  if (threadIdx.x < 128) s_kx[threadIdx.x] = knotsE[threadIdx.x];
  __syncthreads();
  int i = blockIdx.x * blockDim.x + threadIdx.x;
  if (i >= E) return;
  int s = srcA[i], d = dstA[i];
  float x = eattr[i];
  int lo = 0, hi = 128;
  while (lo < hi) { int mid = (lo + hi) >> 1; if (s_kx[mid] < x) lo = mid + 1; else hi = mid; }
  int pos = row_start[d] + atomicAdd(&cursor[d], 1);
  csr[pos] = make_int2(s | (lo << 17), __float_as_int(x));
}

// per-node aggregate: agg[v] = sum_edges relu(h[src] + (A_s x + B_s)) + EPS
// block = 4 waves, one node per wave, lane owns 4 dims (float4).
__global__ void aggregate_kernel(const float* __restrict__ h, const int2* __restrict__ csr,
                                 const int* __restrict__ row_start,
                                 const float* __restrict__ segA, const float* __restrict__ segB,
                                 float* __restrict__ agg, int n) {
  int wv = threadIdx.x >> 6, lane = threadIdx.x & 63;
  int v = blockIdx.x * 4 + wv;
  if (v >= n) return;
  int p0 = row_start[v], p1 = row_start[v + 1];
  f32x4 acc = {0.f, 0.f, 0.f, 0.f};
  for (int p = p0; p < p1; ++p) {
    int2 se = csr[p];
    int srcN = se.x & 0x1FFFF;
    int seg = ((unsigned)se.x) >> 17;
    float x = __int_as_float(se.y);
    f32x4 hv = *(const f32x4*)(h + (size_t)srcN * 256 + lane * 4);
    f32x4 Av = *(const f32x4*)(segA + seg * 256 + lane * 4);
    f32x4 Bv = *(const f32x4*)(segB + seg * 256 + lane * 4);
    acc.x += fmaxf(hv.x + fmaf(Av.x, x, Bv.x), 0.0f) + EPS_F;
    acc.y += fmaxf(hv.y + fmaf(Av.y, x, Bv.y), 0.0f) + EPS_F;
    acc.z += fmaxf(hv.z + fmaf(Av.z, x, Bv.z), 0.0f) + EPS_F;
    acc.w += fmaxf(hv.w + fmaf(Av.w, x, Bv.w), 0.0f) + EPS_F;
  }
  *(f32x4*)(agg + (size_t)v * 256 + lane * 4) = acc;
}

// convert gnn_w [4][K=256][N=256] f32 -> WT [4][N][K] bf16
__global__ void convw_kernel(const float* __restrict__ W, short* __restrict__ WT) {
  int l = blockIdx.x >> 8, nn = blockIdx.x & 255, k = threadIdx.x;
  WT[((size_t)l * 256 + nn) * 256 + k] = f2bf(W[((size_t)l * 256 + k) * 256 + nn]);
}

// hout = (agg + h) @ W + bias, bf16 MFMA 16x16x32, f32 accum.
// block = 4 waves; block tile M=16 rows x N=256; wave owns 64 cols.
__global__ void gemm_kernel(const float* __restrict__ agg, const float* __restrict__ h,
                            const short* __restrict__ WT, const float* __restrict__ bias,
                            float* __restrict__ hout, int M) {
  int wv = threadIdx.x >> 6, lane = threadIdx.x & 63;
  int r0 = blockIdx.x * 16;
  int row = r0 + (lane & 15);
  if (row >= M) row = M - 1;  // clamp; stores guarded below
  int kgrp = (lane >> 4) * 8;
  int c0 = wv * 64;
  int colb = lane & 15;
  f32x4 acc0 = {0.f,0.f,0.f,0.f}, acc1 = acc0, acc2 = acc0, acc3 = acc0;
  const float* arow = agg + (size_t)row * 256;
  const float* hrow = h + (size_t)row * 256;
#pragma unroll
  for (int kt = 0; kt < 8; ++kt) {
    int k0 = kt * 32 + kgrp;
    f32x4 a0 = *(const f32x4*)(arow + k0);
    f32x4 a1 = *(const f32x4*)(arow + k0 + 4);
    f32x4 h0 = *(const f32x4*)(hrow + k0);
    f32x4 h1 = *(const f32x4*)(hrow + k0 + 4);
    short8 af;
    af[0] = f2bf(a0.x + h0.x); af[1] = f2bf(a0.y + h0.y);
    af[2] = f2bf(a0.z + h0.z); af[3] = f2bf(a0.w + h0.w);
    af[4] = f2bf(a1.x + h1.x); af[5] = f2bf(a1.y + h1.y);
    af[6] = f2bf(a1.z + h1.z); af[7] = f2bf(a1.w + h1.w);
    short8 b0 = *(const short8*)(WT + (size_t)(c0 +  0 + colb) * 256 + k0);
    short8 b1 = *(const short8*)(WT + (size_t)(c0 + 16 + colb) * 256 + k0);
    short8 b2 = *(const short8*)(WT + (size_t)(c0 + 32 + colb) * 256 + k0);
    short8 b3 = *(const short8*)(WT + (size_t)(c0 + 48 + colb) * 256 + k0);
    acc0 = __builtin_amdgcn_mfma_f32_16x16x32_bf16(af, b0, acc0, 0, 0, 0);
    acc1 = __builtin_amdgcn_mfma_f32_16x16x32_bf16(af, b1, acc1, 0, 0, 0);
    acc2 = __builtin_amdgcn_mfma_f32_16x16x32_bf16(af, b2, acc2, 0, 0, 0);
    acc3 = __builtin_amdgcn_mfma_f32_16x16x32_bf16(af, b3, acc3, 0, 0, 0);
  }
  int rbase = r0 + (lane >> 4) * 4;
#pragma unroll
  for (int nb = 0; nb < 4; ++nb) {
    f32x4 a = (nb == 0) ? acc0 : (nb == 1) ? acc1 : (nb == 2) ? acc2 : acc3;
    int col = c0 + nb * 16 + colb;
    float bv = bias[col];
#pragma unroll
    for (int r = 0; r < 4; ++r) {
      int rr = rbase + r;
      if (rr < M) hout[(size_t)rr * 256 + col] = a[r] + bv;
    }
  }
}

// out = h @ out_w[256,3] + out_b ; one node per wave
__global__ void head_kernel(const float* __restrict__ h, const float* __restrict__ ow,
                            const float* __restrict__ ob, float* __restrict__ out, int n) {
  __shared__ float sw[768];
  for (int i = threadIdx.x; i < 768; i += 256) sw[i] = ow[i];
  __syncthreads();
  int wv = threadIdx.x >> 6, lane = threadIdx.x & 63;
  int v = blockIdx.x * 4 + wv;
  if (v >= n) return;
  f32x4 hv = *(const f32x4*)(h + (size_t)v * 256 + lane * 4);
  int d0 = lane * 4;
#pragma unroll
  for (int o = 0; o < 3; ++o) {
    float s = hv.x * sw[(d0 + 0) * 3 + o] + hv.y * sw[(d0 + 1) * 3 + o] +
              hv.z * sw[(d0 + 2) * 3 + o] + hv.w * sw[(d0 + 3) * 3 + o];
#pragma unroll
    for (int off = 32; off > 0; off >>= 1) s += __shfl_down(s, off);
    if (lane == 0) out[(size_t)v * 3 + o] = s + ob[o];
  }
}

// ---------------------------------------------------------------------------
extern "C" void kernel_launch(void* const* d_in, const int* in_sizes, int n_in,
                              void* d_out, int out_size, void* d_ws, size_t ws_size,
                              hipStream_t stream) {
  const float* x     = (const float*)d_in[0];
  const float* eattr = (const float*)d_in[1];
  const int*   eidx  = (const int*)d_in[2];
  const float* nw1 = (const float*)d_in[3];
  const float* nb1 = (const float*)d_in[4];
  const float* nw2 = (const float*)d_in[5];
  const float* nb2 = (const float*)d_in[6];
  const float* ew1 = (const float*)d_in[7];
  const float* eb1 = (const float*)d_in[8];
  const float* ew2 = (const float*)d_in[9];
  const float* eb2 = (const float*)d_in[10];
  const float* gw  = (const float*)d_in[11];
  const float* gb  = (const float*)d_in[12];
  const float* ow  = (const float*)d_in[13];
  const float* ob  = (const float*)d_in[14];

  int N = in_sizes[0];
  int E = in_sizes[1];
  const int* srcA = eidx;
  const int* dstA = eidx + E;

  char* ws = (char*)d_ws;
  auto al = [](size_t v) { return (v + 255) & ~(size_t)255; };
  size_t off = 0;
  float* hA   = (float*)(ws + off); off = al(off + (size_t)N * 256 * 4);
  float* hB   = (float*)(ws + off); off = al(off + (size_t)N * 256 * 4);
  float* agg  = (float*)(ws + off); off = al(off + (size_t)N * 256 * 4);
  short* WT   = (short*)(ws + off); off = al(off + (size_t)4 * 256 * 256 * 2);
  float* knN  = (float*)(ws + off); off = al(off + 128 * 4);
  float* AN   = (float*)(ws + off); off = al(off + 129 * 256 * 4);
  float* BN   = (float*)(ws + off); off = al(off + 129 * 256 * 4);
  float* knE  = (float*)(ws + off); off = al(off + 128 * 4);
  float* AE   = (float*)(ws + off); off = al(off + 129 * 256 * 4);
  float* BE   = (float*)(ws + off); off = al(off + 129 * 256 * 4);
  int* rowSt  = (int*)(ws + off);   off = al(off + (size_t)(N + 1) * 4);
  int* counts = (int*)(ws + off);   off = al(off + (size_t)N * 4);
  int2* csr   = (int2*)(ws + off);  off = al(off + (size_t)E * 8);
  (void)ws_size; (void)n_in; (void)out_size;

  // encoder tables
  build_table_kernel<<<1, 256, 0, stream>>>(nw1, nb1, nw2, nb2, knN, AN, BN);
  build_table_kernel<<<1, 256, 0, stream>>>(ew1, eb1, ew2, eb2, knE, AE, BE);

  // node encoder -> hA
  apply_enc_kernel<<<(N + 15) / 16, 256, 0, stream>>>(x, N, knN, AN, BN, hA);

  // CSR build
  int gN = (N + 255) / 256, gE = (E + 255) / 256;
  zero_kernel<<<gN, 256, 0, stream>>>(counts, N);
  hist_kernel<<<gE, 256, 0, stream>>>(dstA, E, counts);
  scan_kernel<<<1, 256, 0, stream>>>(counts, rowSt, N);
  zero_kernel<<<gN, 256, 0, stream>>>(counts, N);
  fill_kernel<<<gE, 256, 0, stream>>>(srcA, dstA, eattr, E, rowSt, counts, knE, csr);

  // weights -> bf16 transposed
  convw_kernel<<<4 * 256, 256, 0, stream>>>(gw, WT);

  float* hc = hA;
  float* hn = hB;
  int gAgg = (N + 3) / 4;
  int gGemm = (N + 15) / 16;
  for (int l = 0; l < 4; ++l) {
    aggregate_kernel<<<gAgg, 256, 0, stream>>>(hc, csr, rowSt, AE, BE, agg, N);
    gemm_kernel<<<gGemm, 256, 0, stream>>>(agg, hc, WT + (size_t)l * 256 * 256,
                                           gb + (size_t)l * 256, hn, N);
    float* t = hc; hc = hn; hn = t;
  }

  head_kernel<<<(N + 3) / 4, 256, 0, stream>>>(hc, ow, ob, (float*)d_out, N);
}

// Round 2
// 608.590 us; speedup vs baseline: 1.2062x; 1.2062x over previous
//
#include <hip/hip_runtime.h>
#include <stdint.h>

#define EPS_F 1e-7f

typedef float f32x4 __attribute__((ext_vector_type(4)));
typedef short short8 __attribute__((ext_vector_type(8)));

__device__ __forceinline__ short f2bf(float f) {
  unsigned u = __float_as_uint(f);
  unsigned r = u + 0x7FFFu + ((u >> 16) & 1u);
  return (short)(r >> 16);
}

// ---------------------------------------------------------------------------
// Build piecewise-linear table for  f(x) = relu(x*w1 + b1) @ W2 + b2
// (scalar x -> R^256).  129 segments, knots at -b1_j/w1_j.
// One block, 256 threads.
// ---------------------------------------------------------------------------
__global__ void build_table_kernel(const float* __restrict__ w1, const float* __restrict__ b1,
                                   const float* __restrict__ w2, const float* __restrict__ b2,
                                   float* __restrict__ knots, float* __restrict__ segA,
                                   float* __restrict__ segB) {
  __shared__ float s_w1[128], s_b1[128], s_kx[128];
  __shared__ int s_sidx[128];
  __shared__ unsigned char s_act0[128];
  int t = threadIdx.x;
  if (t < 128) {
    float w = w1[t], b = b1[t];
    s_w1[t] = w; s_b1[t] = b;
    float kx = (w != 0.0f) ? (-b / w) : 3.4e38f;
    s_kx[t] = kx;
    s_act0[t] = (w < 0.0f) || (w == 0.0f && b > 0.0f);  // active at x = -inf
  }
  __syncthreads();
  if (t < 128) {
    float kx = s_kx[t];
    int r = 0;
    for (int i = 0; i < 128; ++i) {
      float o = s_kx[i];
      if (o < kx || (o == kx && i < t)) ++r;
    }
    s_sidx[r] = t;
  }
  __syncthreads();
  if (t < 128) knots[t] = s_kx[s_sidx[t]];
  // per-dim prefix walk over sorted knots (t = output dim 0..255)
  float A = 0.0f, B = b2[t];
  for (int j = 0; j < 128; ++j) {
    if (s_act0[j]) {
      float w2v = w2[j * 256 + t];
      A += s_w1[j] * w2v;
      B += s_b1[j] * w2v;
    }
  }
  segA[t] = A; segB[t] = B;
  for (int sN = 0; sN < 128; ++sN) {
    int j = s_sidx[sN];
    float sign = s_act0[j] ? -1.0f : 1.0f;
    float w2v = w2[j * 256 + t];
    A += sign * s_w1[j] * w2v;
    B += sign * s_b1[j] * w2v;
    segA[(sN + 1) * 256 + t] = A;
    segB[(sN + 1) * 256 + t] = B;
  }
}

// ---------------------------------------------------------------------------
// Apply encoder table to scalar rows -> f32 [n,256]
// ---------------------------------------------------------------------------
__global__ void apply_enc_kernel(const float* __restrict__ in, int nrows,
                                 const float* __restrict__ knots, const float* __restrict__ segA,
                                 const float* __restrict__ segB, float* __restrict__ out) {
  __shared__ float s_kx[128];
  int t = threadIdx.x;
  if (t < 128) s_kx[t] = knots[t];
  __syncthreads();
  int r0 = blockIdx.x * 16;
  int rEnd = r0 + 16;
  if (rEnd > nrows) rEnd = nrows;
  for (int r = r0; r < rEnd; ++r) {
    float x = in[r];
    int lo = 0, hi = 128;
    while (lo < hi) { int mid = (lo + hi) >> 1; if (s_kx[mid] < x) lo = mid + 1; else hi = mid; }
    out[(size_t)r * 256 + t] = fmaf(segA[lo * 256 + t], x, segB[lo * 256 + t]);
  }
}

__global__ void zero_kernel(int* __restrict__ p, int n) {
  int i = blockIdx.x * blockDim.x + threadIdx.x;
  if (i < n) p[i] = 0;
}

__global__ void hist_kernel(const int* __restrict__ dst, int E, int* __restrict__ counts) {
  int i = blockIdx.x * blockDim.x + threadIdx.x;
  if (i < E) atomicAdd(&counts[dst[i]], 1);
}

// ---------------------------------------------------------------------------
// 3-phase exclusive scan of counts[0..n) -> row_start[0..n], row_start[n]=E
// chunk = 256 elements per block.
// ---------------------------------------------------------------------------
__global__ void scan_p1_kernel(const int* __restrict__ counts, int n,
                               int* __restrict__ blocksums) {
  __shared__ int tmp[256];
  int t = threadIdx.x;
  int i = blockIdx.x * 256 + t;
  tmp[t] = (i < n) ? counts[i] : 0;
  __syncthreads();
  for (int off = 128; off > 0; off >>= 1) {
    if (t < off) tmp[t] += tmp[t + off];
    __syncthreads();
  }
  if (t == 0) blocksums[blockIdx.x] = tmp[0];
}

// single block: exclusive scan of blocksums[0..nb) in place (nb <= 256)
__global__ void scan_p2_kernel(int* __restrict__ blocksums, int nb) {
  __shared__ int tmp[256];
  int t = threadIdx.x;
  int v = (t < nb) ? blocksums[t] : 0;
  tmp[t] = v;
  __syncthreads();
  for (int off = 1; off < 256; off <<= 1) {
    int add = (t >= off) ? tmp[t - off] : 0;
    __syncthreads();
    tmp[t] += add;
    __syncthreads();
  }
  if (t < nb) blocksums[t] = tmp[t] - v;  // exclusive
}

__global__ void scan_p3_kernel(const int* __restrict__ counts, int n, int E,
                               const int* __restrict__ blocksums,
                               int* __restrict__ row_start) {
  __shared__ int tmp[256];
  int t = threadIdx.x;
  int i = blockIdx.x * 256 + t;
  int v = (i < n) ? counts[i] : 0;
  tmp[t] = v;
  __syncthreads();
  for (int off = 1; off < 256; off <<= 1) {
    int add = (t >= off) ? tmp[t - off] : 0;
    __syncthreads();
    tmp[t] += add;
    __syncthreads();
  }
  if (i < n) row_start[i] = blocksums[blockIdx.x] + tmp[t] - v;
  if (blockIdx.x == 0 && t == 0) row_start[n] = E;
}

// fill CSR: per edge, slot under its dst; entry packs {src | seg<<17, bits(x)}
__global__ void fill_kernel(const int* __restrict__ srcA, const int* __restrict__ dstA,
                            const float* __restrict__ eattr, int E,
                            const int* __restrict__ row_start, int* __restrict__ cursor,
                            const float* __restrict__ knotsE, int2* __restrict__ csr) {
  __shared__ float s_kx[128];
  if (threadIdx.x < 128) s_kx[threadIdx.x] = knotsE[threadIdx.x];
  __syncthreads();
  int i = blockIdx.x * blockDim.x + threadIdx.x;
  if (i >= E) return;
  int s = srcA[i], d = dstA[i];
  float x = eattr[i];
  int lo = 0, hi = 128;
  while (lo < hi) { int mid = (lo + hi) >> 1; if (s_kx[mid] < x) lo = mid + 1; else hi = mid; }
  int pos = row_start[d] + atomicAdd(&cursor[d], 1);
  csr[pos] = make_int2(s | (lo << 17), __float_as_int(x));
}

// per-node aggregate: agg[v] = sum_edges relu(h[src] + (A_s x + B_s)) + EPS
// block = 4 waves, one node per wave, lane owns 4 dims (float4).
__global__ void aggregate_kernel(const float* __restrict__ h, const int2* __restrict__ csr,
                                 const int* __restrict__ row_start,
                                 const float* __restrict__ segA, const float* __restrict__ segB,
                                 float* __restrict__ agg, int n) {
  int wv = threadIdx.x >> 6, lane = threadIdx.x & 63;
  int v = blockIdx.x * 4 + wv;
  if (v >= n) return;
  int p0 = row_start[v], p1 = row_start[v + 1];
  f32x4 acc = {0.f, 0.f, 0.f, 0.f};
  for (int p = p0; p < p1; ++p) {
    int2 se = csr[p];
    int srcN = se.x & 0x1FFFF;
    int seg = ((unsigned)se.x) >> 17;
    float x = __int_as_float(se.y);
    f32x4 hv = *(const f32x4*)(h + (size_t)srcN * 256 + lane * 4);
    f32x4 Av = *(const f32x4*)(segA + seg * 256 + lane * 4);
    f32x4 Bv = *(const f32x4*)(segB + seg * 256 + lane * 4);
    acc.x += fmaxf(hv.x + fmaf(Av.x, x, Bv.x), 0.0f) + EPS_F;
    acc.y += fmaxf(hv.y + fmaf(Av.y, x, Bv.y), 0.0f) + EPS_F;
    acc.z += fmaxf(hv.z + fmaf(Av.z, x, Bv.z), 0.0f) + EPS_F;
    acc.w += fmaxf(hv.w + fmaf(Av.w, x, Bv.w), 0.0f) + EPS_F;
  }
  *(f32x4*)(agg + (size_t)v * 256 + lane * 4) = acc;
}

// convert gnn_w [4][K=256][N=256] f32 -> WT [4][N][K] bf16
__global__ void convw_kernel(const float* __restrict__ W, short* __restrict__ WT) {
  int l = blockIdx.x >> 8, nn = blockIdx.x & 255, k = threadIdx.x;
  WT[((size_t)l * 256 + nn) * 256 + k] = f2bf(W[((size_t)l * 256 + k) * 256 + nn]);
}

// hout = (agg + h) @ W + bias, bf16 MFMA 16x16x32, f32 accum.
// block = 4 waves; block tile M=16 rows x N=256; wave owns 64 cols.
__global__ void gemm_kernel(const float* __restrict__ agg, const float* __restrict__ h,
                            const short* __restrict__ WT, const float* __restrict__ bias,
                            float* __restrict__ hout, int M) {
  int wv = threadIdx.x >> 6, lane = threadIdx.x & 63;
  int r0 = blockIdx.x * 16;
  int row = r0 + (lane & 15);
  if (row >= M) row = M - 1;  // clamp; stores guarded below
  int kgrp = (lane >> 4) * 8;
  int c0 = wv * 64;
  int colb = lane & 15;
  f32x4 acc0 = {0.f,0.f,0.f,0.f}, acc1 = acc0, acc2 = acc0, acc3 = acc0;
  const float* arow = agg + (size_t)row * 256;
  const float* hrow = h + (size_t)row * 256;
#pragma unroll
  for (int kt = 0; kt < 8; ++kt) {
    int k0 = kt * 32 + kgrp;
    f32x4 a0 = *(const f32x4*)(arow + k0);
    f32x4 a1 = *(const f32x4*)(arow + k0 + 4);
    f32x4 h0 = *(const f32x4*)(hrow + k0);
    f32x4 h1 = *(const f32x4*)(hrow + k0 + 4);
    short8 af;
    af[0] = f2bf(a0.x + h0.x); af[1] = f2bf(a0.y + h0.y);
    af[2] = f2bf(a0.z + h0.z); af[3] = f2bf(a0.w + h0.w);
    af[4] = f2bf(a1.x + h1.x); af[5] = f2bf(a1.y + h1.y);
    af[6] = f2bf(a1.z + h1.z); af[7] = f2bf(a1.w + h1.w);
    short8 b0 = *(const short8*)(WT + (size_t)(c0 +  0 + colb) * 256 + k0);
    short8 b1 = *(const short8*)(WT + (size_t)(c0 + 16 + colb) * 256 + k0);
    short8 b2 = *(const short8*)(WT + (size_t)(c0 + 32 + colb) * 256 + k0);
    short8 b3 = *(const short8*)(WT + (size_t)(c0 + 48 + colb) * 256 + k0);
    acc0 = __builtin_amdgcn_mfma_f32_16x16x32_bf16(af, b0, acc0, 0, 0, 0);
    acc1 = __builtin_amdgcn_mfma_f32_16x16x32_bf16(af, b1, acc1, 0, 0, 0);
    acc2 = __builtin_amdgcn_mfma_f32_16x16x32_bf16(af, b2, acc2, 0, 0, 0);
    acc3 = __builtin_amdgcn_mfma_f32_16x16x32_bf16(af, b3, acc3, 0, 0, 0);
  }
  int rbase = r0 + (lane >> 4) * 4;
#pragma unroll
  for (int nb = 0; nb < 4; ++nb) {
    f32x4 a = (nb == 0) ? acc0 : (nb == 1) ? acc1 : (nb == 2) ? acc2 : acc3;
    int col = c0 + nb * 16 + colb;
    float bv = bias[col];
#pragma unroll
    for (int r = 0; r < 4; ++r) {
      int rr = rbase + r;
      if (rr < M) hout[(size_t)rr * 256 + col] = a[r] + bv;
    }
  }
}

// out = h @ out_w[256,3] + out_b ; one node per wave
__global__ void head_kernel(const float* __restrict__ h, const float* __restrict__ ow,
                            const float* __restrict__ ob, float* __restrict__ out, int n) {
  __shared__ float sw[768];
  for (int i = threadIdx.x; i < 768; i += 256) sw[i] = ow[i];
  __syncthreads();
  int wv = threadIdx.x >> 6, lane = threadIdx.x & 63;
  int v = blockIdx.x * 4 + wv;
  if (v >= n) return;
  f32x4 hv = *(const f32x4*)(h + (size_t)v * 256 + lane * 4);
  int d0 = lane * 4;
#pragma unroll
  for (int o = 0; o < 3; ++o) {
    float s = hv.x * sw[(d0 + 0) * 3 + o] + hv.y * sw[(d0 + 1) * 3 + o] +
              hv.z * sw[(d0 + 2) * 3 + o] + hv.w * sw[(d0 + 3) * 3 + o];
#pragma unroll
    for (int off = 32; off > 0; off >>= 1) s += __shfl_down(s, off);
    if (lane == 0) out[(size_t)v * 3 + o] = s + ob[o];
  }
}

// ---------------------------------------------------------------------------
extern "C" void kernel_launch(void* const* d_in, const int* in_sizes, int n_in,
                              void* d_out, int out_size, void* d_ws, size_t ws_size,
                              hipStream_t stream) {
  const float* x     = (const float*)d_in[0];
  const float* eattr = (const float*)d_in[1];
  const int*   eidx  = (const int*)d_in[2];
  const float* nw1 = (const float*)d_in[3];
  const float* nb1 = (const float*)d_in[4];
  const float* nw2 = (const float*)d_in[5];
  const float* nb2 = (const float*)d_in[6];
  const float* ew1 = (const float*)d_in[7];
  const float* eb1 = (const float*)d_in[8];
  const float* ew2 = (const float*)d_in[9];
  const float* eb2 = (const float*)d_in[10];
  const float* gw  = (const float*)d_in[11];
  const float* gb  = (const float*)d_in[12];
  const float* ow  = (const float*)d_in[13];
  const float* ob  = (const float*)d_in[14];

  int N = in_sizes[0];
  int E = in_sizes[1];
  const int* srcA = eidx;
  const int* dstA = eidx + E;

  char* ws = (char*)d_ws;
  auto al = [](size_t v) { return (v + 255) & ~(size_t)255; };
  size_t off = 0;
  float* hA   = (float*)(ws + off); off = al(off + (size_t)N * 256 * 4);
  float* hB   = (float*)(ws + off); off = al(off + (size_t)N * 256 * 4);
  float* agg  = (float*)(ws + off); off = al(off + (size_t)N * 256 * 4);
  short* WT   = (short*)(ws + off); off = al(off + (size_t)4 * 256 * 256 * 2);
  float* knN  = (float*)(ws + off); off = al(off + 128 * 4);
  float* AN   = (float*)(ws + off); off = al(off + 129 * 256 * 4);
  float* BN   = (float*)(ws + off); off = al(off + 129 * 256 * 4);
  float* knE  = (float*)(ws + off); off = al(off + 128 * 4);
  float* AE   = (float*)(ws + off); off = al(off + 129 * 256 * 4);
  float* BE   = (float*)(ws + off); off = al(off + 129 * 256 * 4);
  int* rowSt  = (int*)(ws + off);   off = al(off + (size_t)(N + 1) * 4);
  int* counts = (int*)(ws + off);   off = al(off + (size_t)N * 4);
  int* bsums  = (int*)(ws + off);   off = al(off + 256 * 4);
  int2* csr   = (int2*)(ws + off);  off = al(off + (size_t)E * 8);
  (void)ws_size; (void)n_in; (void)out_size;

  // encoder tables
  build_table_kernel<<<1, 256, 0, stream>>>(nw1, nb1, nw2, nb2, knN, AN, BN);
  build_table_kernel<<<1, 256, 0, stream>>>(ew1, eb1, ew2, eb2, knE, AE, BE);

  // node encoder -> hA
  apply_enc_kernel<<<(N + 15) / 16, 256, 0, stream>>>(x, N, knN, AN, BN, hA);

  // CSR build
  int gN = (N + 255) / 256, gE = (E + 255) / 256;
  zero_kernel<<<gN, 256, 0, stream>>>(counts, N);
  hist_kernel<<<gE, 256, 0, stream>>>(dstA, E, counts);
  scan_p1_kernel<<<gN, 256, 0, stream>>>(counts, N, bsums);
  scan_p2_kernel<<<1, 256, 0, stream>>>(bsums, gN);
  scan_p3_kernel<<<gN, 256, 0, stream>>>(counts, N, E, bsums, rowSt);
  zero_kernel<<<gN, 256, 0, stream>>>(counts, N);
  fill_kernel<<<gE, 256, 0, stream>>>(srcA, dstA, eattr, E, rowSt, counts, knE, csr);

  // weights -> bf16 transposed
  convw_kernel<<<4 * 256, 256, 0, stream>>>(gw, WT);

  float* hc = hA;
  float* hn = hB;
  int gAgg = (N + 3) / 4;
  int gGemm = (N + 15) / 16;
  for (int l = 0; l < 4; ++l) {
    aggregate_kernel<<<gAgg, 256, 0, stream>>>(hc, csr, rowSt, AE, BE, agg, N);
    gemm_kernel<<<gGemm, 256, 0, stream>>>(agg, hc, WT + (size_t)l * 256 * 256,
                                           gb + (size_t)l * 256, hn, N);
    float* t = hc; hc = hn; hn = t;
  }

  head_kernel<<<(N + 3) / 4, 256, 0, stream>>>(hc, ow, ob, (float*)d_out, N);
}

// Round 3
// 424.113 us; speedup vs baseline: 1.7308x; 1.4350x over previous
//
#include <hip/hip_runtime.h>
#include <stdint.h>

#define EPS_F 1e-7f

typedef float f32x4 __attribute__((ext_vector_type(4)));
typedef short short8 __attribute__((ext_vector_type(8)));
typedef unsigned short u16;
typedef unsigned short ushort4v __attribute__((ext_vector_type(4)));
typedef unsigned int uint4v __attribute__((ext_vector_type(4)));

__device__ __forceinline__ short f2bf(float f) {
  unsigned u = __float_as_uint(f);
  unsigned r = u + 0x7FFFu + ((u >> 16) & 1u);
  return (short)(r >> 16);
}
__device__ __forceinline__ float bf2f(u16 u) {
  return __uint_as_float((unsigned)u << 16);
}

// ---------------------------------------------------------------------------
// Encoder tables:  f(x) = relu(x*w1 + b1) @ W2 + b2  (scalar x -> R^256)
// 129 segments with knots at -b1_j/w1_j.
// meta: sorted knots + per-unit rank + sign-at-(-inf). 1 block x 128 thr.
// ---------------------------------------------------------------------------
__global__ void build_meta_kernel(const float* __restrict__ w1, const float* __restrict__ b1,
                                  float* __restrict__ knots, int* __restrict__ jrank,
                                  int* __restrict__ act0) {
  __shared__ float s_kx[128];
  int t = threadIdx.x;  // 0..127
  float w = w1[t], b = b1[t];
  float kx = (w != 0.0f) ? (-b / w) : 3.4e38f;
  s_kx[t] = kx;
  int a0 = (w < 0.0f) || (w == 0.0f && b > 0.0f);  // active at x = -inf
  __syncthreads();
  int r = 0;
  for (int i = 0; i < 128; ++i) {
    float o = s_kx[i];
    if (o < kx || (o == kx && i < t)) ++r;
  }
  jrank[t] = r;
  act0[t] = a0;
  knots[r] = kx;
}

// per-segment coefficients: grid = 129 blocks (seg), 256 threads (dim)
// active(j, s) = act0_j XOR (rank_j < s)
__global__ void build_seg_kernel(const float* __restrict__ w1, const float* __restrict__ b1,
                                 const float* __restrict__ w2, const float* __restrict__ b2,
                                 const int* __restrict__ jrank, const int* __restrict__ act0,
                                 float* __restrict__ segA, float* __restrict__ segB,
                                 unsigned* __restrict__ ABpack) {
  int s = blockIdx.x;   // 0..128
  int t = threadIdx.x;  // 0..255
  __shared__ float s_w1[128], s_b1[128];
  __shared__ int s_on[128];
  if (t < 128) {
    s_w1[t] = w1[t];
    s_b1[t] = b1[t];
    s_on[t] = act0[t] ^ (jrank[t] < s ? 1 : 0);
  }
  __syncthreads();
  float A = 0.0f, B = b2[t];
#pragma unroll 4
  for (int j = 0; j < 128; ++j) {
    if (s_on[j]) {
      float w2v = w2[j * 256 + t];
      A = fmaf(s_w1[j], w2v, A);
      B = fmaf(s_b1[j], w2v, B);
    }
  }
  segA[s * 256 + t] = A;
  segB[s * 256 + t] = B;
  if (ABpack) {
    unsigned a = (unsigned)(u16)f2bf(A);
    unsigned bb = (unsigned)(u16)f2bf(B);
    ABpack[s * 256 + t] = a | (bb << 16);
  }
}

// node encoder applied to x -> bf16 [n,256]
__global__ void apply_enc_kernel(const float* __restrict__ in, int nrows,
                                 const float* __restrict__ knots, const float* __restrict__ segA,
                                 const float* __restrict__ segB, u16* __restrict__ outbf) {
  __shared__ float s_kx[128];
  int t = threadIdx.x;
  if (t < 128) s_kx[t] = knots[t];
  __syncthreads();
  int r0 = blockIdx.x * 16;
  int rEnd = r0 + 16;
  if (rEnd > nrows) rEnd = nrows;
  for (int r = r0; r < rEnd; ++r) {
    float x = in[r];
    int lo = 0, hi = 128;
    while (lo < hi) { int mid = (lo + hi) >> 1; if (s_kx[mid] < x) lo = mid + 1; else hi = mid; }
    outbf[(size_t)r * 256 + t] = (u16)f2bf(fmaf(segA[lo * 256 + t], x, segB[lo * 256 + t]));
  }
}

__global__ void zero_kernel(int* __restrict__ p, int n) {
  int i = blockIdx.x * blockDim.x + threadIdx.x;
  if (i < n) p[i] = 0;
}

__global__ void hist_kernel(const int* __restrict__ dst, int E, int* __restrict__ counts) {
  int i = blockIdx.x * blockDim.x + threadIdx.x;
  if (i < E) atomicAdd(&counts[dst[i]], 1);
}

// 3-phase exclusive scan of counts[0..n) -> row_start[0..n], row_start[n]=E
__global__ void scan_p1_kernel(const int* __restrict__ counts, int n,
                               int* __restrict__ blocksums) {
  __shared__ int tmp[256];
  int t = threadIdx.x;
  int i = blockIdx.x * 256 + t;
  tmp[t] = (i < n) ? counts[i] : 0;
  __syncthreads();
  for (int off = 128; off > 0; off >>= 1) {
    if (t < off) tmp[t] += tmp[t + off];
    __syncthreads();
  }
  if (t == 0) blocksums[blockIdx.x] = tmp[0];
}

__global__ void scan_p2_kernel(int* __restrict__ blocksums, int nb) {
  __shared__ int tmp[256];
  int t = threadIdx.x;
  int v = (t < nb) ? blocksums[t] : 0;
  tmp[t] = v;
  __syncthreads();
  for (int off = 1; off < 256; off <<= 1) {
    int add = (t >= off) ? tmp[t - off] : 0;
    __syncthreads();
    tmp[t] += add;
    __syncthreads();
  }
  if (t < nb) blocksums[t] = tmp[t] - v;  // exclusive
}

__global__ void scan_p3_kernel(const int* __restrict__ counts, int n, int E,
                               const int* __restrict__ blocksums,
                               int* __restrict__ row_start) {
  __shared__ int tmp[256];
  int t = threadIdx.x;
  int i = blockIdx.x * 256 + t;
  int v = (i < n) ? counts[i] : 0;
  tmp[t] = v;
  __syncthreads();
  for (int off = 1; off < 256; off <<= 1) {
    int add = (t >= off) ? tmp[t - off] : 0;
    __syncthreads();
    tmp[t] += add;
    __syncthreads();
  }
  if (i < n) row_start[i] = blocksums[blockIdx.x] + tmp[t] - v;
  if (blockIdx.x == 0 && t == 0) row_start[n] = E;
}

// fill CSR: per edge, slot under its dst; entry packs {src | seg<<17, bits(x)}
__global__ void fill_kernel(const int* __restrict__ srcA, const int* __restrict__ dstA,
                            const float* __restrict__ eattr, int E,
                            const int* __restrict__ row_start, int* __restrict__ cursor,
                            const float* __restrict__ knotsE, int2* __restrict__ csr) {
  __shared__ float s_kx[128];
  if (threadIdx.x < 128) s_kx[threadIdx.x] = knotsE[threadIdx.x];
  __syncthreads();
  int i = blockIdx.x * blockDim.x + threadIdx.x;
  if (i >= E) return;
  int s = srcA[i], d = dstA[i];
  float x = eattr[i];
  int lo = 0, hi = 128;
  while (lo < hi) { int mid = (lo + hi) >> 1; if (s_kx[mid] < x) lo = mid + 1; else hi = mid; }
  int pos = row_start[d] + atomicAdd(&cursor[d], 1);
  csr[pos] = make_int2(s | (lo << 17), __float_as_int(x));
}

// convert gnn_w [4][K=256][N=256] f32 -> WT [4][N][K] bf16
__global__ void convw_kernel(const float* __restrict__ W, short* __restrict__ WT) {
  int l = blockIdx.x >> 8, nn = blockIdx.x & 255, k = threadIdx.x;
  WT[((size_t)l * 256 + nn) * 256 + k] = f2bf(W[((size_t)l * 256 + k) * 256 + nn]);
}

// ---------------------------------------------------------------------------
// Fused layer: per block of 16 nodes:
//  phase 1: wave w aggregates nodes w*4..w*4+3 (edge gather, bf16 h + packed
//           bf16 (A,B) tables), A-row = h[v] + sum relu(...) + deg*eps -> LDS bf16
//  phase 2: 16x256 @ 256x256 MFMA from LDS A-tile, WT prefetch double-buffer.
// hout f32 written only when houtf != null (last layer); bf16 when houtbf != null.
// ---------------------------------------------------------------------------
__global__ __launch_bounds__(256) void layer_kernel(
    const u16* __restrict__ hbf, const int2* __restrict__ csr,
    const int* __restrict__ row_start, const unsigned* __restrict__ AB,
    const short* __restrict__ WT, const float* __restrict__ bias,
    float* __restrict__ houtf, u16* __restrict__ houtbf, int N) {
  __shared__ u16 As[16][264];  // +8 pad -> 2-way-max bank pattern on b128 reads
  int wv = threadIdx.x >> 6, lane = threadIdx.x & 63;
  int nbase = blockIdx.x * 16;
  int d0 = lane * 4;

  // ---- phase 1: aggregate 4 nodes per wave ----
  for (int i = 0; i < 4; ++i) {
    int r = wv * 4 + i;
    int v = nbase + r;
    f32x4 acc = {0.f, 0.f, 0.f, 0.f};
    if (v < N) {
      ushort4v sv = *(const ushort4v*)(hbf + (size_t)v * 256 + d0);
      acc.x = bf2f(sv.x); acc.y = bf2f(sv.y); acc.z = bf2f(sv.z); acc.w = bf2f(sv.w);
      int p0 = row_start[v], p1 = row_start[v + 1];
      int2 se_n = {0, 0};
      ushort4v hv_n = {0, 0, 0, 0};
      uint4v ab_n = {0, 0, 0, 0};
      if (p0 < p1) {
        se_n = csr[p0];
        int sN = se_n.x & 0x1FFFF, sg = ((unsigned)se_n.x) >> 17;
        hv_n = *(const ushort4v*)(hbf + (size_t)sN * 256 + d0);
        ab_n = *(const uint4v*)(AB + (size_t)sg * 256 + d0);
      }
      for (int p = p0; p < p1; ++p) {
        int2 se = se_n;
        ushort4v hv = hv_n;
        uint4v ab = ab_n;
        if (p + 1 < p1) {  // prefetch next edge (hides gather latency)
          se_n = csr[p + 1];
          int sN = se_n.x & 0x1FFFF, sg = ((unsigned)se_n.x) >> 17;
          hv_n = *(const ushort4v*)(hbf + (size_t)sN * 256 + d0);
          ab_n = *(const uint4v*)(AB + (size_t)sg * 256 + d0);
        }
        float x = __int_as_float(se.y);
#pragma unroll
        for (int j = 0; j < 4; ++j) {
          float Af = __uint_as_float(ab[j] << 16);
          float Bf = __uint_as_float(ab[j] & 0xFFFF0000u);
          float m = fmaf(Af, x, Bf);
          float tt = bf2f(hv[j]) + m;
          acc[j] += fmaxf(tt, 0.0f);
        }
      }
      float de = (float)(p1 - p0) * EPS_F;
      acc.x += de; acc.y += de; acc.z += de; acc.w += de;
    }
    ushort4v ob;
    ob.x = (u16)f2bf(acc.x); ob.y = (u16)f2bf(acc.y);
    ob.z = (u16)f2bf(acc.z); ob.w = (u16)f2bf(acc.w);
    *(ushort4v*)&As[r][d0] = ob;
  }
  __syncthreads();

  // ---- phase 2: [16,256] @ [256,256] ----
  int colb = lane & 15, rowf = lane & 15, kgrp = (lane >> 4) * 8;
  int c0 = wv * 64;
  const short* wtc = WT + (size_t)(c0 + colb) * 256;
  const u16* Ar = &As[rowf][0];
  f32x4 acc0 = {0.f, 0.f, 0.f, 0.f}, acc1 = acc0, acc2 = acc0, acc3 = acc0;
  short8 b0 = *(const short8*)(wtc + kgrp);
  short8 b1 = *(const short8*)(wtc + 4096 + kgrp);
  short8 b2 = *(const short8*)(wtc + 8192 + kgrp);
  short8 b3 = *(const short8*)(wtc + 12288 + kgrp);
#pragma unroll
  for (int kt = 0; kt < 8; ++kt) {
    int k0 = kt * 32 + kgrp;
    short8 af = *(const short8*)(Ar + k0);
    short8 n0, n1, n2, n3;
    if (kt < 7) {
      int kn = k0 + 32;
      n0 = *(const short8*)(wtc + kn);
      n1 = *(const short8*)(wtc + 4096 + kn);
      n2 = *(const short8*)(wtc + 8192 + kn);
      n3 = *(const short8*)(wtc + 12288 + kn);
    }
    acc0 = __builtin_amdgcn_mfma_f32_16x16x32_bf16(af, b0, acc0, 0, 0, 0);
    acc1 = __builtin_amdgcn_mfma_f32_16x16x32_bf16(af, b1, acc1, 0, 0, 0);
    acc2 = __builtin_amdgcn_mfma_f32_16x16x32_bf16(af, b2, acc2, 0, 0, 0);
    acc3 = __builtin_amdgcn_mfma_f32_16x16x32_bf16(af, b3, acc3, 0, 0, 0);
    if (kt < 7) { b0 = n0; b1 = n1; b2 = n2; b3 = n3; }
  }
  int rbase = (lane >> 4) * 4;
#pragma unroll
  for (int nb = 0; nb < 4; ++nb) {
    f32x4 a = (nb == 0) ? acc0 : (nb == 1) ? acc1 : (nb == 2) ? acc2 : acc3;
    int col = c0 + nb * 16 + colb;
    float bv = bias[col];
#pragma unroll
    for (int rr = 0; rr < 4; ++rr) {
      int vv = nbase + rbase + rr;
      if (vv < N) {
        float val = a[rr] + bv;
        if (houtf) houtf[(size_t)vv * 256 + col] = val;
        if (houtbf) houtbf[(size_t)vv * 256 + col] = (u16)f2bf(val);
      }
    }
  }
}

// out = h @ out_w[256,3] + out_b ; one node per wave
__global__ void head_kernel(const float* __restrict__ h, const float* __restrict__ ow,
                            const float* __restrict__ ob, float* __restrict__ out, int n) {
  __shared__ float sw[768];
  for (int i = threadIdx.x; i < 768; i += 256) sw[i] = ow[i];
  __syncthreads();
  int wv = threadIdx.x >> 6, lane = threadIdx.x & 63;
  int v = blockIdx.x * 4 + wv;
  if (v >= n) return;
  f32x4 hv = *(const f32x4*)(h + (size_t)v * 256 + lane * 4);
  int d0 = lane * 4;
#pragma unroll
  for (int o = 0; o < 3; ++o) {
    float s = hv.x * sw[(d0 + 0) * 3 + o] + hv.y * sw[(d0 + 1) * 3 + o] +
              hv.z * sw[(d0 + 2) * 3 + o] + hv.w * sw[(d0 + 3) * 3 + o];
#pragma unroll
    for (int off = 32; off > 0; off >>= 1) s += __shfl_down(s, off);
    if (lane == 0) out[(size_t)v * 3 + o] = s + ob[o];
  }
}

// ---------------------------------------------------------------------------
extern "C" void kernel_launch(void* const* d_in, const int* in_sizes, int n_in,
                              void* d_out, int out_size, void* d_ws, size_t ws_size,
                              hipStream_t stream) {
  const float* x     = (const float*)d_in[0];
  const float* eattr = (const float*)d_in[1];
  const int*   eidx  = (const int*)d_in[2];
  const float* nw1 = (const float*)d_in[3];
  const float* nb1 = (const float*)d_in[4];
  const float* nw2 = (const float*)d_in[5];
  const float* nb2 = (const float*)d_in[6];
  const float* ew1 = (const float*)d_in[7];
  const float* eb1 = (const float*)d_in[8];
  const float* ew2 = (const float*)d_in[9];
  const float* eb2 = (const float*)d_in[10];
  const float* gw  = (const float*)d_in[11];
  const float* gb  = (const float*)d_in[12];
  const float* ow  = (const float*)d_in[13];
  const float* ob  = (const float*)d_in[14];

  int N = in_sizes[0];
  int E = in_sizes[1];
  const int* srcA = eidx;
  const int* dstA = eidx + E;

  char* ws = (char*)d_ws;
  auto al = [](size_t v) { return (v + 255) & ~(size_t)255; };
  size_t off = 0;
  float* hA    = (float*)(ws + off); off = al(off + (size_t)N * 256 * 4);   // final f32 h
  u16* hbfA    = (u16*)(ws + off);   off = al(off + (size_t)N * 256 * 2);
  u16* hbfB    = (u16*)(ws + off);   off = al(off + (size_t)N * 256 * 2);
  short* WT    = (short*)(ws + off); off = al(off + (size_t)4 * 256 * 256 * 2);
  float* knN   = (float*)(ws + off); off = al(off + 128 * 4);
  float* AN    = (float*)(ws + off); off = al(off + 129 * 256 * 4);
  float* BN    = (float*)(ws + off); off = al(off + 129 * 256 * 4);
  float* knE   = (float*)(ws + off); off = al(off + 128 * 4);
  float* AE    = (float*)(ws + off); off = al(off + 129 * 256 * 4);
  float* BE    = (float*)(ws + off); off = al(off + 129 * 256 * 4);
  unsigned* ABE = (unsigned*)(ws + off); off = al(off + 129 * 256 * 4);
  int* rankN   = (int*)(ws + off);   off = al(off + 128 * 4);
  int* act0N   = (int*)(ws + off);   off = al(off + 128 * 4);
  int* rankE   = (int*)(ws + off);   off = al(off + 128 * 4);
  int* act0E   = (int*)(ws + off);   off = al(off + 128 * 4);
  int* rowSt   = (int*)(ws + off);   off = al(off + (size_t)(N + 1) * 4);
  int* counts  = (int*)(ws + off);   off = al(off + (size_t)N * 4);
  int* bsums   = (int*)(ws + off);   off = al(off + 256 * 4);
  int2* csr    = (int2*)(ws + off);  off = al(off + (size_t)E * 8);
  (void)ws_size; (void)n_in; (void)out_size;

  // encoder tables (parallel build)
  build_meta_kernel<<<1, 128, 0, stream>>>(nw1, nb1, knN, rankN, act0N);
  build_meta_kernel<<<1, 128, 0, stream>>>(ew1, eb1, knE, rankE, act0E);
  build_seg_kernel<<<129, 256, 0, stream>>>(nw1, nb1, nw2, nb2, rankN, act0N, AN, BN, nullptr);
  build_seg_kernel<<<129, 256, 0, stream>>>(ew1, eb1, ew2, eb2, rankE, act0E, AE, BE, ABE);

  // node encoder -> hbfA
  apply_enc_kernel<<<(N + 15) / 16, 256, 0, stream>>>(x, N, knN, AN, BN, hbfA);

  // CSR build
  int gN = (N + 255) / 256, gE = (E + 255) / 256;
  zero_kernel<<<gN, 256, 0, stream>>>(counts, N);
  hist_kernel<<<gE, 256, 0, stream>>>(dstA, E, counts);
  scan_p1_kernel<<<gN, 256, 0, stream>>>(counts, N, bsums);
  scan_p2_kernel<<<1, 256, 0, stream>>>(bsums, gN);
  scan_p3_kernel<<<gN, 256, 0, stream>>>(counts, N, E, bsums, rowSt);
  zero_kernel<<<gN, 256, 0, stream>>>(counts, N);
  fill_kernel<<<gE, 256, 0, stream>>>(srcA, dstA, eattr, E, rowSt, counts, knE, csr);

  // weights -> bf16 transposed
  convw_kernel<<<4 * 256, 256, 0, stream>>>(gw, WT);

  // fused layers
  u16* hbc = hbfA;
  u16* hbn = hbfB;
  int gLayer = (N + 15) / 16;
  for (int l = 0; l < 4; ++l) {
    float* hf = (l == 3) ? hA : nullptr;      // f32 only needed by head
    u16* hbo = (l == 3) ? nullptr : hbn;
    layer_kernel<<<gLayer, 256, 0, stream>>>(hbc, csr, rowSt, ABE,
                                             WT + (size_t)l * 256 * 256,
                                             gb + (size_t)l * 256, hf, hbo, N);
    u16* t = hbc; hbc = hbn; hbn = t;
  }

  head_kernel<<<(N + 3) / 4, 256, 0, stream>>>(hA, ow, ob, (float*)d_out, N);
}